// Round 4
// baseline (1087.853 us; speedup 1.0000x reference)
//
#include <hip/hip_runtime.h>

#define P_TOT 5456
#define NANCH 49104
#define KTOP 1000
#define CAND_CAP 4096

typedef unsigned long long u64;
typedef unsigned int u32;

__device__ __forceinline__ void level_of(int p, int& l, int& off, int& W, int& sh) {
  if (p < 4096)      { l = 0; off = 0;    W = 64; sh = 6; }
  else if (p < 5120) { l = 1; off = 4096; W = 32; sh = 5; }
  else if (p < 5376) { l = 2; off = 5120; W = 16; sh = 4; }
  else if (p < 5440) { l = 3; off = 5376; W = 8;  sh = 3; }
  else               { l = 4; off = 5440; W = 4;  sh = 2; }
}

// ---------------- FPN input convs ----------------
__global__ void k_conv1x1_in(const float* __restrict__ x, const float* __restrict__ w,
                             const float* __restrict__ b, float* __restrict__ F,
                             int Cin, int npix, int off) {
  int p = blockIdx.x * 256 + threadIdx.x;
  if (p >= npix) return;
  int oc4 = blockIdx.y * 4;
  float acc[4] = {0.f,0.f,0.f,0.f};
  for (int c = 0; c < Cin; ++c) {
    float xv = x[c * npix + p];
#pragma unroll
    for (int o = 0; o < 4; ++o)
      acc[o] = fmaf(w[(oc4 + o) * Cin + c], xv, acc[o]);
  }
#pragma unroll
  for (int o = 0; o < 4; ++o)
    F[(off + p) * 64 + oc4 + o] = acc[o] + b[oc4 + o];
}

// c5 1x1: 64 blocks (one oc each) x 256 threads (one pixel each)
__global__ void k_conv1x1_c5(const float* __restrict__ x, const float* __restrict__ w,
                             const float* __restrict__ b, float* __restrict__ F) {
  int oc = blockIdx.x;
  int p = threadIdx.x;
  float acc = 0.f;
  for (int c = 0; c < 192; ++c)
    acc = fmaf(w[oc * 192 + c], x[c * 256 + p], acc);
  F[(5120 + p) * 64 + oc] = acc + b[oc];
}

// p6 conv 3x3 s2: 64 blocks (oc) x 256 threads (64 pix x 4 cgroups of 48ch), LDS reduce
__global__ void k_conv_p6(const float* __restrict__ c5, const float* __restrict__ w,
                          const float* __restrict__ b, float* __restrict__ F) {
  int oc = blockIdx.x;
  int tid = threadIdx.x;
  int cg = tid >> 6, pix = tid & 63;
  int oy = pix >> 3, ox = pix & 7;
  float acc = 0.f;
  int c0 = cg * 48;
  for (int c = c0; c < c0 + 48; ++c) {
    const float* xc = c5 + c * 256;
    const float* wc = w + (oc * 192 + c) * 9;
#pragma unroll
    for (int ky = 0; ky < 3; ++ky) {
      int iy = oy * 2 + ky - 1;
      if ((unsigned)iy >= 16u) continue;
#pragma unroll
      for (int kx = 0; kx < 3; ++kx) {
        int ix = ox * 2 + kx - 1;
        if ((unsigned)ix >= 16u) continue;
        acc = fmaf(wc[ky * 3 + kx], xc[iy * 16 + ix], acc);
      }
    }
  }
  __shared__ float red[4][64];
  red[cg][pix] = acc;
  __syncthreads();
  if (cg == 0) {
    float s = red[0][pix] + red[1][pix] + red[2][pix] + red[3][pix] + b[oc];
    F[(5376 + pix) * 64 + oc] = s;
  }
}

// p7 conv 3x3 s2 on relu(p6): 64 blocks (oc) x 64 threads (16 pix x 4 cgroups of 16ch)
__global__ void k_conv_p7(const float* __restrict__ w, const float* __restrict__ b,
                          float* __restrict__ F) {
  int oc = blockIdx.x;
  int t = threadIdx.x;
  int cg = t >> 4, pix = t & 15;
  int oy = pix >> 2, ox = pix & 3;
  float acc = 0.f;
  int c0 = cg * 16;
  for (int c = c0; c < c0 + 16; ++c) {
#pragma unroll
    for (int ky = 0; ky < 3; ++ky) {
      int iy = oy * 2 + ky - 1;
      if ((unsigned)iy >= 8u) continue;
#pragma unroll
      for (int kx = 0; kx < 3; ++kx) {
        int ix = ox * 2 + kx - 1;
        if ((unsigned)ix >= 8u) continue;
        float xv = fmaxf(F[(5376 + iy * 8 + ix) * 64 + c], 0.f);  // relu(p6)
        acc = fmaf(w[(oc * 64 + c) * 9 + ky * 3 + kx], xv, acc);
      }
    }
  }
  acc += __shfl_down(acc, 32);
  acc += __shfl_down(acc, 16);
  if (cg == 0)
    F[(5440 + pix) * 64 + oc] = acc + b[oc];
}

// ---------------- BiFPN td / out stages (LDS-staged GEMM) ----------------
__global__ __launch_bounds__(256) void k_td_s(const float* __restrict__ Fin, float* __restrict__ TD,
                     const float* __restrict__ tw, const float* __restrict__ tb,
                     const float* __restrict__ tg, const float* __restrict__ tbt,
                     const float* __restrict__ tm, const float* __restrict__ tv,
                     const float* __restrict__ w1raw, int blk) {
  int S = blockIdx.x * 64;
  int l, off, W, sh; level_of(S, l, off, W, sh);
  if (l == 4) {  // p7td = p7x (copy)
    for (int j = threadIdx.x; j < 1024; j += 256) {
      int pixrel = j >> 4, c4 = j & 15;
      int pix = S + pixrel;
      if (pix < P_TOT)
        *(float4*)(TD + pix * 64 + c4 * 4) = *(const float4*)(Fin + pix * 64 + c4 * 4);
    }
    return;
  }
  float wav = fmaxf(w1raw[blk * 2 + 0], 0.f);
  float wbv = fmaxf(w1raw[blk * 2 + 1], 0.f);
  float s = wav + wbv + 1e-4f;
  wav /= s; wbv /= s;
  __shared__ float4 tile[16][65];
  for (int j = threadIdx.x; j < 1024; j += 256) {
    int pixrel = j >> 4, c4 = j & 15;
    int pix = S + pixrel;
    int lo = pix - off, yy = lo >> sh, xx = lo & (W - 1);
    int Wu = W >> 1;
    int pup = off + W * W + (yy >> 1) * Wu + (xx >> 1);
    float4 a = *(const float4*)(Fin + pix * 64 + c4 * 4);
    float4 bq = *(const float4*)(Fin + pup * 64 + c4 * 4);
    float4 r;
    r.x = wav * a.x + wbv * bq.x; r.y = wav * a.y + wbv * bq.y;
    r.z = wav * a.z + wbv * bq.z; r.w = wav * a.w + wbv * bq.w;
    tile[c4][pixrel] = r;
  }
  __syncthreads();
  int lane = threadIdx.x & 63;
  int wid = __builtin_amdgcn_readfirstlane(threadIdx.x >> 6);
  int idxbase = (blk * 5 + l) * 64;
  const float* wt = tw + (size_t)idxbase * 64;
  float acc[16] = {};
#pragma unroll 4
  for (int c4 = 0; c4 < 16; ++c4) {
    float4 xv = tile[c4][lane];
#pragma unroll
    for (int o = 0; o < 16; ++o) {
      float4 wv = *(const float4*)(wt + (wid * 16 + o) * 64 + c4 * 4);
      acc[o] = fmaf(xv.x, wv.x, fmaf(xv.y, wv.y, fmaf(xv.z, wv.z, fmaf(xv.w, wv.w, acc[o]))));
    }
  }
  int px = S + lane;
#pragma unroll
  for (int o = 0; o < 16; ++o) {
    int idx = idxbase + wid * 16 + o;
    float xv = acc[o] + tb[idx];
    float inv = 1.0f / sqrtf(tv[idx] + 4e-5f);
    TD[px * 64 + wid * 16 + o] = (xv - tm[idx]) * (tg[idx] * inv) + tbt[idx];
  }
}

__global__ __launch_bounds__(256) void k_out_s(const float* __restrict__ Fin, const float* __restrict__ TD,
                      float* __restrict__ OUT,
                      const float* __restrict__ ow, const float* __restrict__ ob,
                      const float* __restrict__ og, const float* __restrict__ obt,
                      const float* __restrict__ om, const float* __restrict__ ov,
                      const float* __restrict__ w2raw, int blk) {
  int S = blockIdx.x * 64;
  int l, off, W, sh; level_of(S, l, off, W, sh);
  if (l == 0) {  // new feats level3 = p3td
    for (int j = threadIdx.x; j < 1024; j += 256) {
      int pixrel = j >> 4, c4 = j & 15;
      int pix = S + pixrel;
      *(float4*)(OUT + pix * 64 + c4 * 4) = *(const float4*)(TD + pix * 64 + c4 * 4);
    }
    return;
  }
  float wav = fmaxf(w2raw[blk * 3 + 0], 0.f);
  float wbv = fmaxf(w2raw[blk * 3 + 1], 0.f);
  float wcv = fmaxf(w2raw[blk * 3 + 2], 0.f);
  float s = wav + wbv + wcv + 1e-4f;
  wav /= s; wbv /= s; wcv /= s;
  __shared__ float4 tile[16][65];
  for (int j = threadIdx.x; j < 1024; j += 256) {
    int pixrel = j >> 4, c4 = j & 15;
    int pix = S + pixrel;
    if (pix < P_TOT) {
      int lo = pix - off, yy = lo >> sh, xx = lo & (W - 1);
      int Wd = W << 1;
      int offd = off - Wd * Wd;
      int pdn = offd + (2 * yy) * Wd + 2 * xx;
      float4 a = *(const float4*)(Fin + pix * 64 + c4 * 4);
      float4 bq = *(const float4*)(TD + pix * 64 + c4 * 4);
      float4 cq = *(const float4*)(TD + pdn * 64 + c4 * 4);
      float4 r;
      r.x = wav * a.x + wbv * bq.x + wcv * cq.x;
      r.y = wav * a.y + wbv * bq.y + wcv * cq.y;
      r.z = wav * a.z + wbv * bq.z + wcv * cq.z;
      r.w = wav * a.w + wbv * bq.w + wcv * cq.w;
      tile[c4][pixrel] = r;
    } else {
      tile[c4][pixrel] = make_float4(0.f, 0.f, 0.f, 0.f);
    }
  }
  __syncthreads();
  int lane = threadIdx.x & 63;
  int wid = __builtin_amdgcn_readfirstlane(threadIdx.x >> 6);
  int idxbase = (blk * 5 + l) * 64;
  const float* wt = ow + (size_t)idxbase * 64;
  float acc[16] = {};
#pragma unroll 4
  for (int c4 = 0; c4 < 16; ++c4) {
    float4 xv = tile[c4][lane];
#pragma unroll
    for (int o = 0; o < 16; ++o) {
      float4 wv = *(const float4*)(wt + (wid * 16 + o) * 64 + c4 * 4);
      acc[o] = fmaf(xv.x, wv.x, fmaf(xv.y, wv.y, fmaf(xv.z, wv.z, fmaf(xv.w, wv.w, acc[o]))));
    }
  }
  int px = S + lane;
  if (px < P_TOT) {
#pragma unroll
    for (int o = 0; o < 16; ++o) {
      int idx = idxbase + wid * 16 + o;
      float xv = acc[o] + ob[idx];
      float inv = 1.0f / sqrtf(ov[idx] + 4e-5f);
      OUT[px * 64 + wid * 16 + o] = (xv - om[idx]) * (og[idx] * inv) + obt[idx];
    }
  }
}

// ---------------- head conv weight repack: [oc][c][k] -> [k][oc][c] ----------------
__global__ void k_repack(const float* __restrict__ src, float* __restrict__ dst,
                         int OC, int total) {
  int idx = blockIdx.x * 256 + threadIdx.x;
  if (idx >= total) return;
  int per = OC * 576;
  int layer = idx / per;
  int rem = idx - layer * per;
  int oc = rem / 576;
  int r2 = rem - oc * 576;
  int c = r2 / 9;
  int k = r2 - c * 9;
  dst[layer * per + (k * OC + oc) * 64 + c] = src[idx];
}

// ---------------- head 3x3 conv, LDS-staged ----------------
// Block: 64 pixels (one chunk, never crosses level boundary) x OCB out-channels.
// LDS tile: [c4][pixel] float4, pixels [S-W-1, S+W+65) clamped to level; col 201 = zeros
// (border taps redirect there). Waves own oc-quarters via readfirstlane -> scalar w loads.
template<int OPT>
__global__ __launch_bounds__(256) void k_conv3s(const float* __restrict__ F, float* __restrict__ O,
                         const float* __restrict__ RW, const float* __restrict__ bias,
                         int OC, int OCB, int nchunk, int relu) {
  int S = blockIdx.x * 64;
  int l, off, W, sh; level_of(S, l, off, W, sh);
  int tilebase = S - W - 1;
  int clo = max(off, tilebase);
  int chi = min(off + W * W, tilebase + 201);
  __shared__ float4 tile[16][203];
  for (int j = threadIdx.x; j < 16 * 202; j += 256) {
    int pixrel = j >> 4, c4 = j & 15;
    int pix = tilebase + pixrel;
    float4 v = make_float4(0.f, 0.f, 0.f, 0.f);
    if (pix >= clo && pix < chi) v = *(const float4*)(F + pix * 64 + c4 * 4);
    tile[c4][pixrel] = v;
  }
  __syncthreads();
  int lane = threadIdx.x & 63;
  int wid = __builtin_amdgcn_readfirstlane(threadIdx.x >> 6);
  int px = S + lane;
  int loc = px - off, y = loc >> sh, x = loc & (W - 1);
  int rel[9];
#pragma unroll
  for (int ky = 0; ky < 3; ++ky)
#pragma unroll
    for (int kx = 0; kx < 3; ++kx) {
      int iy = y + ky - 1, ix = x + kx - 1;
      bool v = ((unsigned)iy < (unsigned)W) && ((unsigned)ix < (unsigned)W);
      rel[ky * 3 + kx] = v ? (lane + (W + 1) + (ky - 1) * W + (kx - 1)) : 201;
    }
  bool pxok = px < P_TOT;
  for (int ch = 0; ch < nchunk; ++ch) {
    int ocb = blockIdx.y * OCB + wid * (OCB >> 2) + ch * OPT;
    float acc[OPT];
#pragma unroll
    for (int o = 0; o < OPT; ++o) acc[o] = 0.f;
#pragma unroll
    for (int t = 0; t < 9; ++t) {
      const float* wb = RW + (t * OC + ocb) * 64;
      int r = rel[t];
#pragma unroll 4
      for (int c4 = 0; c4 < 16; ++c4) {
        float4 xv = tile[c4][r];
#pragma unroll
        for (int o = 0; o < OPT; ++o) {
          float4 wv = *(const float4*)(wb + o * 64 + c4 * 4);
          acc[o] = fmaf(xv.x, wv.x, fmaf(xv.y, wv.y, fmaf(xv.z, wv.z, fmaf(xv.w, wv.w, acc[o]))));
        }
      }
    }
    if (pxok) {
#pragma unroll
      for (int o = 0; o < OPT; ++o) {
        float v = acc[o] + bias[ocb + o];
        if (relu) v = fmaxf(v, 0.f);
        O[px * OC + ocb + o] = v;
      }
    }
  }
}

// ---------------- decode boxes + score/label + histogram pass A ----------------
__global__ void k_decode_score(const float* __restrict__ REG, const float* __restrict__ CLS,
                               float* __restrict__ score, int* __restrict__ label,
                               float* __restrict__ boxes, u32* __restrict__ ukey,
                               u32* __restrict__ hist1) {
  int aid = blockIdx.x * 256 + threadIdx.x;
  if (aid >= NANCH) return;
  int p = aid / 9;
  int a = aid - p * 9;
  int l, off, W, sh; level_of(p, l, off, W, sh);
  int loc = p - off, y = loc >> sh, x = loc & (W - 1);
  int s_idx = a % 3, r_idx = a / 3;
  double scale = (s_idx == 0) ? 1.0 : ((s_idx == 1) ? 1.2599210498948732 : 1.5874010519681994);
  double ratio = (r_idx == 0) ? 0.5 : ((r_idx == 1) ? 1.0 : 2.0);
  double strided = (double)(8 << l);
  double based = (double)(32 << l);
  double w0 = based * scale;
  double wA = sqrt(w0 * w0 / ratio);
  double hA = wA * ratio;
  double cxd = (x + 0.5) * strided;
  double cyd = (y + 0.5) * strided;
  float ax1 = (float)(cxd - wA / 2.0);
  float ay1 = (float)(cyd - hA / 2.0);
  float ax2 = (float)(cxd + wA / 2.0);
  float ay2 = (float)(cyd + hA / 2.0);
  float wa = ax2 - ax1, ha = ay2 - ay1;
  float cxa = ax1 + 0.5f * wa, cya = ay1 + 0.5f * ha;
  const float* rg = REG + p * 36 + a * 4;
  float r0 = rg[0], r1 = rg[1], r2 = rg[2], r3 = rg[3];
  float ncx = cxa + (r0 * 0.1f) * wa;
  float ncy = cya + (r1 * 0.1f) * ha;
  float nw = expf(r2 * 0.2f) * wa;
  float nh = expf(r3 * 0.2f) * ha;
  float bx1 = fmaxf(ncx - 0.5f * nw, 0.f);
  float by1 = fmaxf(ncy - 0.5f * nh, 0.f);
  float bx2 = fminf(ncx + 0.5f * nw, 512.f);
  float by2 = fminf(ncy + 0.5f * nh, 512.f);
  boxes[aid * 4 + 0] = bx1; boxes[aid * 4 + 1] = by1;
  boxes[aid * 4 + 2] = bx2; boxes[aid * 4 + 3] = by2;
  const float* lg = CLS + p * 720 + a * 80;
  float best = lg[0]; int bl = 0;
  for (int c = 1; c < 80; ++c) {
    float v = lg[c];
    if (v > best) { best = v; bl = c; }
  }
  float sc = 1.f / (1.f + expf(-best));
  score[aid] = sc; label[aid] = bl;
  u32 u = 0u;
  if (sc > 0.05f) u = __float_as_uint(sc) | 0x80000000u;
  ukey[aid] = u;
  if (u) atomicAdd(&hist1[u >> 16], 1u);
}

// ---------------- radix-select scans ----------------
__global__ __launch_bounds__(1024) void k_scanA(const u32* __restrict__ hist, u32* __restrict__ ctrl) {
  __shared__ u32 cs[1024];
  u32 s = 0;
  int base = threadIdx.x * 64;
  for (int b = 0; b < 64; ++b) s += hist[base + b];
  cs[threadIdx.x] = s;
  __syncthreads();
  if (threadIdx.x == 0) {
    u32 cum = 0; int cc = -1;
    for (int tt = 1023; tt >= 0; --tt) {
      if (cum + cs[tt] >= (u32)KTOP) { cc = tt; break; }
      cum += cs[tt];
    }
    if (cc < 0) {
      ctrl[0] = 0x20000u; ctrl[1] = cum; ctrl[2] = 1u;
    } else {
      u32 c2 = cum; int B1 = cc * 64;
      for (int b = cc * 64 + 63; b >= cc * 64; --b) {
        u32 h = hist[b];
        if (c2 + h >= (u32)KTOP) { B1 = b; break; }
        c2 += h;
      }
      ctrl[0] = (u32)B1; ctrl[1] = c2;
    }
  }
}

__global__ void k_histB(const u32* __restrict__ ukey, u32* __restrict__ hist2,
                        const u32* __restrict__ ctrl) {
  int aid = blockIdx.x * 256 + threadIdx.x;
  if (aid >= NANCH) return;
  u32 u = ukey[aid];
  if (u && (u >> 16) == ctrl[0]) atomicAdd(&hist2[u & 0xFFFFu], 1u);
}

__global__ __launch_bounds__(1024) void k_scanB(const u32* __restrict__ hist, u32* __restrict__ ctrl) {
  if (ctrl[0] > 0xFFFFu) return;
  __shared__ u32 cs[1024];
  u32 s = 0;
  int base = threadIdx.x * 64;
  for (int b = 0; b < 64; ++b) s += hist[base + b];
  cs[threadIdx.x] = s;
  __syncthreads();
  if (threadIdx.x == 0) {
    u32 CA = ctrl[1];
    u32 cum = CA; int cc = -1;
    for (int tt = 1023; tt >= 0; --tt) {
      if (cum + cs[tt] >= (u32)KTOP) { cc = tt; break; }
      cum += cs[tt];
    }
    u32 B2 = 0;
    if (cc >= 0) {
      for (int b = cc * 64 + 63; b >= cc * 64; --b) {
        u32 h = hist[b];
        if (cum + h >= (u32)KTOP) { B2 = (u32)b; break; }
        cum += h;
      }
    }
    ctrl[2] = (ctrl[0] << 16) | B2;
  }
}

__global__ void k_compact(const u32* __restrict__ ukey, u64* __restrict__ cand,
                          u32* __restrict__ ctrl) {
  int aid = blockIdx.x * 256 + threadIdx.x;
  if (aid >= NANCH) return;
  u32 u = ukey[aid];
  u32 T = ctrl[2];
  if (u >= T && u != 0) {
    u32 pos = atomicAdd(&ctrl[3], 1u);
    if (pos < (u32)CAND_CAP)
      cand[pos] = (((u64)u) << 32) | (u32)(~(u32)aid);
  }
}

// ---------------- bitonic sort + select top-1000 ----------------
__global__ __launch_bounds__(1024) void k_sortsel(const u64* __restrict__ cand, u32* __restrict__ ctrl,
                                                  const float* __restrict__ score, const int* __restrict__ label,
                                                  const float* __restrict__ boxes,
                                                  float* __restrict__ tops, int* __restrict__ topl,
                                                  float* __restrict__ topb) {
  __shared__ u64 key[CAND_CAP];
  int C = min((int)ctrl[3], CAND_CAP);
  for (int i = threadIdx.x; i < CAND_CAP; i += 1024) key[i] = (i < C) ? cand[i] : 0ULL;
  __syncthreads();
  for (int k = 2; k <= CAND_CAP; k <<= 1) {
    for (int j = k >> 1; j > 0; j >>= 1) {
      for (int t = threadIdx.x; t < CAND_CAP / 2; t += 1024) {
        int i1 = ((t & ~(j - 1)) << 1) | (t & (j - 1));
        int i2 = i1 + j;
        bool up = (i1 & k) != 0;
        u64 a = key[i1], b = key[i2];
        bool sw = up ? (a > b) : (a < b);
        if (sw) { key[i1] = b; key[i2] = a; }
      }
      __syncthreads();
    }
  }
  if (threadIdx.x < KTOP) {
    int r = threadIdx.x;
    u64 kk = key[r];
    u32 u = (u32)(kk >> 32);
    if (u != 0) {
      int aid = (int)(~((u32)kk));
      float sv = __uint_as_float(u & 0x7FFFFFFFu);
      tops[r] = sv; topl[r] = label[aid];
      topb[r * 4 + 0] = boxes[aid * 4 + 0];
      topb[r * 4 + 1] = boxes[aid * 4 + 1];
      topb[r * 4 + 2] = boxes[aid * 4 + 2];
      topb[r * 4 + 3] = boxes[aid * 4 + 3];
    } else {
      tops[r] = -1.f; topl[r] = -1;
      topb[r * 4 + 0] = 0.f; topb[r * 4 + 1] = 0.f;
      topb[r * 4 + 2] = 0.f; topb[r * 4 + 3] = 0.f;
    }
  }
  if (threadIdx.x == 0) ctrl[4] = (u32)min(C, KTOP);
}

// ---------------- NMS ----------------
__global__ void k_iou(const float* __restrict__ topb, const u32* __restrict__ ctrl,
                      u64* __restrict__ mask) {
  int wid = threadIdx.x >> 6, lane = threadIdx.x & 63;
  int i = blockIdx.x * 4 + wid;
  int V = (int)ctrl[4];
  if (i >= V) return;
  float x1i = topb[i * 4], y1i = topb[i * 4 + 1], x2i = topb[i * 4 + 2], y2i = topb[i * 4 + 3];
  float ai = fmaxf(x2i - x1i, 0.f) * fmaxf(y2i - y1i, 0.f);
  for (int w = 0; w < 16; ++w) {
    int j = w * 64 + lane;
    bool bit = false;
    if (j < KTOP && j > i) {
      float x1j = topb[j * 4], y1j = topb[j * 4 + 1], x2j = topb[j * 4 + 2], y2j = topb[j * 4 + 3];
      float aj = fmaxf(x2j - x1j, 0.f) * fmaxf(y2j - y1j, 0.f);
      float iw = fmaxf(fminf(x2i, x2j) - fmaxf(x1i, x1j), 0.f);
      float ih = fmaxf(fminf(y2i, y2j) - fmaxf(y1i, y1j), 0.f);
      float inter = iw * ih;
      float iou = inter / (ai + aj - inter + 1e-8f);
      bit = iou > 0.5f;
    }
    u64 m = __ballot(bit);
    if (lane == 0) mask[i * 16 + w] = m;
  }
}

__global__ __launch_bounds__(64) void k_nms(const u64* __restrict__ mask,
                                            const float* __restrict__ tops,
                                            int* __restrict__ keep) {
  const int la = threadIdx.x;
  const int rg = la >> 4;
  const int wg = la & 15;
  u64 remw = 0ULL;

#define LOADB(b, upd, intra, vsc) do {                                   \
    int rb = (b) * 64;                                                   \
    _Pragma("unroll")                                                    \
    for (int k = 0; k < 16; ++k)                                         \
      upd[k] = mask[(u32)(rb + rg + 4 * k) * 16u + (u32)wg];             \
    intra = mask[(u32)(rb + la) * 16u + (u32)(b)];                       \
    vsc = tops[rb + la];                                                 \
  } while (0)

#define PROC(b, upd, intra, vsc) do {                                    \
    u64 validmask = __ballot((vsc) > 0.05f);                             \
    u32 ilo = (u32)(intra);                                              \
    u32 ihi = (u32)((intra) >> 32);                                      \
    u64 supmask = ((u64)__builtin_amdgcn_readlane((int)(remw >> 32), (b)) << 32) | \
                  (u32)__builtin_amdgcn_readlane((int)(u32)remw, (b));   \
    u64 keptmask = 0ULL;                                                 \
    for (int i = 0; i < 64; ++i) {                                       \
      u32 rlo = (u32)__builtin_amdgcn_readlane((int)ilo, i);             \
      u32 rhi = (u32)__builtin_amdgcn_readlane((int)ihi, i);             \
      u64 take = (u64)0 - (((validmask >> i) & 1ULL) & (~(supmask >> i) & 1ULL)); \
      keptmask |= (1ULL << i) & take;                                    \
      supmask |= (((u64)rhi << 32) | rlo) & take;                        \
    }                                                                    \
    u64 kk = keptmask >> rg;                                             \
    u64 acc = 0ULL;                                                      \
    _Pragma("unroll")                                                    \
    for (int k = 0; k < 16; ++k)                                         \
      if ((kk >> (4 * k)) & 1ULL) acc |= upd[k];                         \
    acc |= __shfl_xor(acc, 16);                                          \
    acc |= __shfl_xor(acc, 32);                                          \
    remw |= acc;                                                         \
    int j = (b) * 64 + la;                                               \
    if (j < KTOP) keep[j] = (int)((keptmask >> la) & 1ULL);              \
  } while (0)

  u64 updA[16], updB[16];
  u64 intraA, intraB;
  float vscA, vscB;
  LOADB(0, updA, intraA, vscA);
  for (int bb = 0; bb < 16; bb += 2) {
    if (bb + 1 < 16) LOADB(bb + 1, updB, intraB, vscB);
    PROC(bb, updA, intraA, vscA);
    if (bb + 2 < 16) LOADB(bb + 2, updA, intraA, vscA);
    if (bb + 1 < 16) PROC(bb + 1, updB, intraB, vscB);
  }
#undef LOADB
#undef PROC
}

__global__ void k_final(const int* __restrict__ keep, const float* __restrict__ tops,
                        const int* __restrict__ topl, const float* __restrict__ topb,
                        float* __restrict__ out) {
  int r = blockIdx.x * 256 + threadIdx.x;
  if (r >= KTOP) return;
  int k = keep[r];
  out[r] = k ? tops[r] : 0.f;
  out[KTOP + r] = k ? (float)topl[r] : -1.f;
  out[2 * KTOP + r * 4 + 0] = k ? topb[r * 4 + 0] : 0.f;
  out[2 * KTOP + r * 4 + 1] = k ? topb[r * 4 + 1] : 0.f;
  out[2 * KTOP + r * 4 + 2] = k ? topb[r * 4 + 2] : 0.f;
  out[2 * KTOP + r * 4 + 3] = k ? topb[r * 4 + 3] : 0.f;
}

extern "C" void kernel_launch(void* const* d_in, const int* in_sizes, int n_in,
                              void* d_out, int out_size, void* d_ws, size_t ws_size,
                              hipStream_t stream) {
  const float* c3    = (const float*)d_in[0];
  const float* c4i   = (const float*)d_in[1];
  const float* c5    = (const float*)d_in[2];
  const float* w3    = (const float*)d_in[3];  const float* b3 = (const float*)d_in[4];
  const float* w4    = (const float*)d_in[5];  const float* b4 = (const float*)d_in[6];
  const float* w5    = (const float*)d_in[7];  const float* b5 = (const float*)d_in[8];
  const float* w6    = (const float*)d_in[9];  const float* b6 = (const float*)d_in[10];
  const float* w7    = (const float*)d_in[11]; const float* b7 = (const float*)d_in[12];
  const float* tdw   = (const float*)d_in[13]; const float* tdb  = (const float*)d_in[14];
  const float* tdg   = (const float*)d_in[15]; const float* tdbt = (const float*)d_in[16];
  const float* tdm   = (const float*)d_in[17]; const float* tdv  = (const float*)d_in[18];
  const float* ow    = (const float*)d_in[19]; const float* ob   = (const float*)d_in[20];
  const float* og    = (const float*)d_in[21]; const float* obt  = (const float*)d_in[22];
  const float* om    = (const float*)d_in[23]; const float* ov   = (const float*)d_in[24];
  const float* w1    = (const float*)d_in[25]; const float* w2   = (const float*)d_in[26];
  const float* clsw  = (const float*)d_in[27]; const float* clsb = (const float*)d_in[28];
  const float* clsow = (const float*)d_in[29]; const float* clsob= (const float*)d_in[30];
  const float* regw  = (const float*)d_in[31]; const float* regb = (const float*)d_in[32];
  const float* regow = (const float*)d_in[33]; const float* regob= (const float*)d_in[34];

  float* ws = (float*)d_ws;
  const size_t NF = 349184;                 // 5456*64
  float* A    = ws;
  float* Bb   = ws + NF;
  float* Cb   = ws + 2 * NF;
  float* RWc  = ws + 3 * NF;                // 110592
  float* RWco = RWc + 110592;               // 414720
  float* RWr  = RWco + 414720;              // 110592
  float* RWro = RWr + 110592;               // 20736
  float* REGb = RWro + 20736;               // 196416
  float* CLSb = REGb + 196416;              // 3928320
  float* scoreb = CLSb + 3928320;           // 49104
  int*   labelb = (int*)(scoreb + 49104);   // 49104
  float* boxesb = (float*)(labelb + 49104); // 196416
  u32* hist1 = (u32*)(boxesb + 196416);     // 65536
  u32* hist2 = hist1 + 65536;               // 65536
  u32* ctrl  = hist2 + 65536;               // 64
  u64* cand  = (u64*)(ctrl + 64);           // 4096 u64
  float* tops = (float*)(cand + CAND_CAP);  // 1024
  int*   topl = (int*)(tops + 1024);        // 1024
  float* topb = (float*)(topl + 1024);      // 4096
  u64*   mask = (u64*)(topb + 4096);        // 16384 u64
  int*   keep = (int*)(mask + 16384);       // 1024
  u32*   ukeyb = (u32*)(keep + 1024);       // 49104

  hipMemsetAsync(hist1, 0, (65536 + 65536 + 64) * sizeof(u32), stream);

  // weight repacks
  k_repack<<<dim3((110592 + 255) / 256), 256, 0, stream>>>(clsw, RWc, 64, 110592);
  k_repack<<<dim3((110592 + 255) / 256), 256, 0, stream>>>(regw, RWr, 64, 110592);
  k_repack<<<dim3((414720 + 255) / 256), 256, 0, stream>>>(clsow, RWco, 720, 414720);
  k_repack<<<dim3((20736 + 255) / 256), 256, 0, stream>>>(regow, RWro, 36, 20736);

  // FPN inputs (batch 0 only)
  k_conv1x1_in<<<dim3(16, 16), 256, 0, stream>>>(c3, w3, b3, A, 40, 4096, 0);
  k_conv1x1_in<<<dim3(4, 16), 256, 0, stream>>>(c4i, w4, b4, A, 80, 1024, 4096);
  k_conv1x1_c5<<<dim3(64), 256, 0, stream>>>(c5, w5, b5, A);
  k_conv_p6<<<dim3(64), 256, 0, stream>>>(c5, w6, b6, A);
  k_conv_p7<<<dim3(64), 64, 0, stream>>>(w7, b7, A);

  // BiFPN x2
  k_td_s<<<dim3(86), 256, 0, stream>>>(A, Bb, tdw, tdb, tdg, tdbt, tdm, tdv, w1, 0);
  k_out_s<<<dim3(86), 256, 0, stream>>>(A, Bb, Cb, ow, ob, og, obt, om, ov, w2, 0);
  k_td_s<<<dim3(86), 256, 0, stream>>>(Cb, Bb, tdw, tdb, tdg, tdbt, tdm, tdv, w1, 1);
  k_out_s<<<dim3(86), 256, 0, stream>>>(Cb, Bb, A, ow, ob, og, obt, om, ov, w2, 1);

  // reg head
  k_conv3s<8><<<dim3(86, 2), 256, 0, stream>>>(A, Bb, RWr, regb, 64, 32, 1, 1);
  k_conv3s<8><<<dim3(86, 2), 256, 0, stream>>>(Bb, Cb, RWr + 36864, regb + 64, 64, 32, 1, 1);
  k_conv3s<8><<<dim3(86, 2), 256, 0, stream>>>(Cb, Bb, RWr + 73728, regb + 128, 64, 32, 1, 1);
  k_conv3s<9><<<dim3(86, 1), 256, 0, stream>>>(Bb, REGb, RWro, regob, 36, 36, 1, 0);
  // cls head
  k_conv3s<8><<<dim3(86, 2), 256, 0, stream>>>(A, Cb, RWc, clsb, 64, 32, 1, 1);
  k_conv3s<8><<<dim3(86, 2), 256, 0, stream>>>(Cb, Bb, RWc + 36864, clsb + 64, 64, 32, 1, 1);
  k_conv3s<8><<<dim3(86, 2), 256, 0, stream>>>(Bb, Cb, RWc + 73728, clsb + 128, 64, 32, 1, 1);
  k_conv3s<10><<<dim3(86, 6), 256, 0, stream>>>(Cb, CLSb, RWco, clsob, 720, 120, 3, 0);

  // decode + score + top-k + NMS
  k_decode_score<<<dim3(192), 256, 0, stream>>>(REGb, CLSb, scoreb, labelb, boxesb, ukeyb, hist1);
  k_scanA<<<dim3(1), 1024, 0, stream>>>(hist1, ctrl);
  k_histB<<<dim3(192), 256, 0, stream>>>(ukeyb, hist2, ctrl);
  k_scanB<<<dim3(1), 1024, 0, stream>>>(hist2, ctrl);
  k_compact<<<dim3(192), 256, 0, stream>>>(ukeyb, cand, ctrl);
  k_sortsel<<<dim3(1), 1024, 0, stream>>>(cand, ctrl, scoreb, labelb, boxesb, tops, topl, topb);
  k_iou<<<dim3(250), 256, 0, stream>>>(topb, ctrl, mask);
  k_nms<<<dim3(1), 64, 0, stream>>>(mask, tops, keep);
  k_final<<<dim3(4), 256, 0, stream>>>(keep, tops, topl, topb, (float*)d_out);
}

// Round 5
// 730.552 us; speedup vs baseline: 1.4891x; 1.4891x over previous
//
#include <hip/hip_runtime.h>

#define P_TOT 5456
#define NANCH 49104
#define KTOP 1000
#define CAND_CAP 4096

typedef unsigned long long u64;
typedef unsigned int u32;

// Blocked-transposed feature layout: float4 index = blk*1024 + c4*64 + pxin
// (64-ch feature; for OC-ch: blk*(OC/4)*64 + c4*64 + pxin)

__device__ __forceinline__ void level_of(int p, int& l, int& off, int& W, int& sh) {
  if (p < 4096)      { l = 0; off = 0;    W = 64; sh = 6; }
  else if (p < 5120) { l = 1; off = 4096; W = 32; sh = 5; }
  else if (p < 5376) { l = 2; off = 5120; W = 16; sh = 4; }
  else if (p < 5440) { l = 3; off = 5376; W = 8;  sh = 3; }
  else               { l = 4; off = 5440; W = 4;  sh = 2; }
}

// ---------------- FPN input convs (blocked writes) ----------------
__global__ void k_conv1x1_in(const float* __restrict__ x, const float* __restrict__ w,
                             const float* __restrict__ b, float4* __restrict__ F4,
                             int Cin, int npix, int off) {
  int p = blockIdx.x * 256 + threadIdx.x;
  if (p >= npix) return;
  int c4o = blockIdx.y;            // output c4 group
  int oc4 = c4o * 4;
  float acc[4] = {0.f,0.f,0.f,0.f};
  for (int c = 0; c < Cin; ++c) {
    float xv = x[c * npix + p];
#pragma unroll
    for (int o = 0; o < 4; ++o)
      acc[o] = fmaf(w[(oc4 + o) * Cin + c], xv, acc[o]);
  }
  int px = off + p;
  float4 r;
  r.x = acc[0] + b[oc4 + 0]; r.y = acc[1] + b[oc4 + 1];
  r.z = acc[2] + b[oc4 + 2]; r.w = acc[3] + b[oc4 + 3];
  F4[((px >> 6) << 10) + (c4o << 6) + (px & 63)] = r;
}

__global__ void k_conv1x1_c5(const float* __restrict__ x, const float* __restrict__ w,
                             const float* __restrict__ b, float* __restrict__ F) {
  int oc = blockIdx.x;
  int p = threadIdx.x;
  float acc = 0.f;
  for (int c = 0; c < 192; ++c)
    acc = fmaf(w[oc * 192 + c], x[c * 256 + p], acc);
  int px = 5120 + p;
  F[((px >> 6) << 12) + ((oc >> 2) << 8) + ((px & 63) << 2) + (oc & 3)] = acc + b[oc];
}

__global__ void k_conv_p6(const float* __restrict__ c5, const float* __restrict__ w,
                          const float* __restrict__ b, float* __restrict__ F) {
  int oc = blockIdx.x;
  int tid = threadIdx.x;
  int cg = tid >> 6, pix = tid & 63;
  int oy = pix >> 3, ox = pix & 7;
  float acc = 0.f;
  int c0 = cg * 48;
  for (int c = c0; c < c0 + 48; ++c) {
    const float* xc = c5 + c * 256;
    const float* wc = w + (oc * 192 + c) * 9;
#pragma unroll
    for (int ky = 0; ky < 3; ++ky) {
      int iy = oy * 2 + ky - 1;
      if ((unsigned)iy >= 16u) continue;
#pragma unroll
      for (int kx = 0; kx < 3; ++kx) {
        int ix = ox * 2 + kx - 1;
        if ((unsigned)ix >= 16u) continue;
        acc = fmaf(wc[ky * 3 + kx], xc[iy * 16 + ix], acc);
      }
    }
  }
  __shared__ float red[4][64];
  red[cg][pix] = acc;
  __syncthreads();
  if (cg == 0) {
    float s = red[0][pix] + red[1][pix] + red[2][pix] + red[3][pix] + b[oc];
    F[(84 << 12) + ((oc >> 2) << 8) + (pix << 2) + (oc & 3)] = s;
  }
}

__global__ void k_conv_p7(const float* __restrict__ w, const float* __restrict__ b,
                          float* __restrict__ F) {
  int oc = blockIdx.x;
  int t = threadIdx.x;
  int cg = t >> 4, pix = t & 15;
  int oy = pix >> 2, ox = pix & 3;
  float acc = 0.f;
  int c0 = cg * 16;
  for (int c = c0; c < c0 + 16; ++c) {
#pragma unroll
    for (int ky = 0; ky < 3; ++ky) {
      int iy = oy * 2 + ky - 1;
      if ((unsigned)iy >= 8u) continue;
#pragma unroll
      for (int kx = 0; kx < 3; ++kx) {
        int ix = ox * 2 + kx - 1;
        if ((unsigned)ix >= 8u) continue;
        float xv = fmaxf(F[(84 << 12) + ((c >> 2) << 8) + ((iy * 8 + ix) << 2) + (c & 3)], 0.f);
        acc = fmaf(w[(oc * 64 + c) * 9 + ky * 3 + kx], xv, acc);
      }
    }
  }
  acc += __shfl_down(acc, 32);
  acc += __shfl_down(acc, 16);
  if (cg == 0)
    F[(85 << 12) + ((oc >> 2) << 8) + (pix << 2) + (oc & 3)] = acc + b[oc];
}

// ---------------- BiFPN td / out (blocked, no LDS) ----------------
__global__ __launch_bounds__(256) void k_td_t(const float4* __restrict__ F4, float4* __restrict__ TD4,
                     const float* __restrict__ tw, const float* __restrict__ tb,
                     const float* __restrict__ tg, const float* __restrict__ tbt,
                     const float* __restrict__ tm, const float* __restrict__ tv,
                     const float* __restrict__ w1raw, int blk) {
  int bx = blockIdx.x, S = bx * 64;
  int l, off, W, sh; level_of(S, l, off, W, sh);
  int tid = threadIdx.x;
  if (l == 4) {                      // p7td = p7x copy (16 px x 16 c4)
    int pxrel = tid >> 4, c4 = tid & 15;
    TD4[(85 << 10) + (c4 << 6) + pxrel] = F4[(85 << 10) + (c4 << 6) + pxrel];
    return;
  }
  float wav = fmaxf(w1raw[blk * 2 + 0], 0.f);
  float wbv = fmaxf(w1raw[blk * 2 + 1], 0.f);
  float s = wav + wbv + 1e-4f;
  wav /= s; wbv /= s;
  int lane = tid & 63;
  int wid = __builtin_amdgcn_readfirstlane(tid >> 6);
  int px = S + lane;
  int loc = px - off, yy = loc >> sh, xx = loc & (W - 1);
  int Wu = W >> 1;
  int pup = off + W * W + (yy >> 1) * Wu + (xx >> 1);
  int fup = ((pup >> 6) << 10) + (pup & 63);
  int fself = (bx << 10) + lane;
  float acc[16] = {};
  const float4* wt4 = (const float4*)tw + (size_t)((blk * 5 + l) * 64) * 16;
#pragma unroll 4
  for (int c4 = 0; c4 < 16; ++c4) {
    float4 a = F4[fself + (c4 << 6)];
    float4 b = F4[fup + (c4 << 6)];
    float4 fin;
    fin.x = wav * a.x + wbv * b.x; fin.y = wav * a.y + wbv * b.y;
    fin.z = wav * a.z + wbv * b.z; fin.w = wav * a.w + wbv * b.w;
#pragma unroll
    for (int o = 0; o < 16; ++o) {
      float4 wv = wt4[(wid * 16 + o) * 16 + c4];
      acc[o] = fmaf(fin.x, wv.x, fmaf(fin.y, wv.y, fmaf(fin.z, wv.z, fmaf(fin.w, wv.w, acc[o]))));
    }
  }
  int idxbase = (blk * 5 + l) * 64 + wid * 16;
#pragma unroll
  for (int q = 0; q < 4; ++q) {
    float r[4];
#pragma unroll
    for (int j = 0; j < 4; ++j) {
      int o = q * 4 + j, idx = idxbase + o;
      float xv = acc[o] + tb[idx];
      float inv = 1.0f / sqrtf(tv[idx] + 4e-5f);
      r[j] = (xv - tm[idx]) * (tg[idx] * inv) + tbt[idx];
    }
    float4 rq; rq.x = r[0]; rq.y = r[1]; rq.z = r[2]; rq.w = r[3];
    TD4[(bx << 10) + ((wid * 4 + q) << 6) + lane] = rq;
  }
}

__global__ __launch_bounds__(256) void k_out_t(const float4* __restrict__ F4, const float4* __restrict__ TD4,
                      float4* __restrict__ OUT4,
                      const float* __restrict__ ow, const float* __restrict__ ob,
                      const float* __restrict__ og, const float* __restrict__ obt,
                      const float* __restrict__ om, const float* __restrict__ ov,
                      const float* __restrict__ w2raw, int blk) {
  int bx = blockIdx.x, S = bx * 64;
  int l, off, W, sh; level_of(S, l, off, W, sh);
  int tid = threadIdx.x;
  if (l == 0) {                      // new feats level3 = p3td copy
    for (int j = tid; j < 1024; j += 256)
      OUT4[(bx << 10) + j] = TD4[(bx << 10) + j];
    return;
  }
  float wav = fmaxf(w2raw[blk * 3 + 0], 0.f);
  float wbv = fmaxf(w2raw[blk * 3 + 1], 0.f);
  float wcv = fmaxf(w2raw[blk * 3 + 2], 0.f);
  float s = wav + wbv + wcv + 1e-4f;
  wav /= s; wbv /= s; wcv /= s;
  int lane = tid & 63;
  int wid = __builtin_amdgcn_readfirstlane(tid >> 6);
  int px = S + lane;
  bool pxok = px < P_TOT;
  int loc = px - off, yy = loc >> sh, xx = loc & (W - 1);
  int Wd = W << 1;
  int offd = off - Wd * Wd;
  int pdn = offd + (2 * yy) * Wd + 2 * xx;
  int fself = (bx << 10) + lane;
  int fdn = pxok ? (((pdn >> 6) << 10) + (pdn & 63)) : fself;
  float acc[16] = {};
  const float4* wt4 = (const float4*)ow + (size_t)((blk * 5 + l) * 64) * 16;
#pragma unroll 4
  for (int c4 = 0; c4 < 16; ++c4) {
    float4 a = F4[fself + (c4 << 6)];
    float4 b = TD4[fself + (c4 << 6)];
    float4 c = TD4[fdn + (c4 << 6)];
    float4 fin;
    fin.x = wav * a.x + wbv * b.x + wcv * c.x;
    fin.y = wav * a.y + wbv * b.y + wcv * c.y;
    fin.z = wav * a.z + wbv * b.z + wcv * c.z;
    fin.w = wav * a.w + wbv * b.w + wcv * c.w;
#pragma unroll
    for (int o = 0; o < 16; ++o) {
      float4 wv = wt4[(wid * 16 + o) * 16 + c4];
      acc[o] = fmaf(fin.x, wv.x, fmaf(fin.y, wv.y, fmaf(fin.z, wv.z, fmaf(fin.w, wv.w, acc[o]))));
    }
  }
  if (!pxok) return;
  int idxbase = (blk * 5 + l) * 64 + wid * 16;
#pragma unroll
  for (int q = 0; q < 4; ++q) {
    float r[4];
#pragma unroll
    for (int j = 0; j < 4; ++j) {
      int o = q * 4 + j, idx = idxbase + o;
      float xv = acc[o] + ob[idx];
      float inv = 1.0f / sqrtf(ov[idx] + 4e-5f);
      r[j] = (xv - om[idx]) * (og[idx] * inv) + obt[idx];
    }
    float4 rq; rq.x = r[0]; rq.y = r[1]; rq.z = r[2]; rq.w = r[3];
    OUT4[(bx << 10) + ((wid * 4 + q) << 6) + lane] = rq;
  }
}

// ---------------- merged weight repack: [oc][c][k] -> [k][oc][c] ----------------
__global__ void k_repack_all(const float* __restrict__ clsw, const float* __restrict__ regw,
                             const float* __restrict__ clsow, const float* __restrict__ regow,
                             float* __restrict__ RWc, float* __restrict__ RWr,
                             float* __restrict__ RWco, float* __restrict__ RWro) {
  int idx = blockIdx.x * 256 + threadIdx.x;
  if (idx >= 656640) return;
  const float* src; float* dst; int OC, local;
  if (idx < 110592)      { src = clsw;  dst = RWc;  OC = 64;  local = idx; }
  else if (idx < 221184) { src = regw;  dst = RWr;  OC = 64;  local = idx - 110592; }
  else if (idx < 635904) { src = clsow; dst = RWco; OC = 720; local = idx - 221184; }
  else                   { src = regow; dst = RWro; OC = 36;  local = idx - 635904; }
  int per = OC * 576;
  int layer = local / per;
  int rem = local - layer * per;
  int oc = rem / 576;
  int r2 = rem - oc * 576;
  int c = r2 / 9;
  int k = r2 - c * 9;
  dst[layer * per + (k * OC + oc) * 64 + c] = src[local];
}

// ---------------- head 3x3 conv, blocked layout, no LDS ----------------
template<int OPT>
__global__ __launch_bounds__(256) void k_conv3t(const float4* __restrict__ F4, float* __restrict__ O,
                         const float* __restrict__ RW, const float* __restrict__ bias,
                         int OC, int relu) {
  int S = blockIdx.x * 64;
  int l, off, W, sh; level_of(S, l, off, W, sh);
  int lane = threadIdx.x & 63;
  int wid = __builtin_amdgcn_readfirstlane(threadIdx.x >> 6);
  int g = blockIdx.y * 4 + wid;
  int ocb = g * OPT;
  if (ocb >= OC) return;
  int px = S + lane;
  int loc = px - off, y = loc >> sh, x = loc & (W - 1);
  int selfidx = ((px >> 6) << 10) + (px & 63);
  int fidx[9]; bool vld[9];
#pragma unroll
  for (int ky = 0; ky < 3; ++ky)
#pragma unroll
    for (int kx = 0; kx < 3; ++kx) {
      int iy = y + ky - 1, ix = x + kx - 1;
      bool v = ((unsigned)iy < (unsigned)W) && ((unsigned)ix < (unsigned)W);
      int pp = px + (ky - 1) * W + (kx - 1);
      int t = ky * 3 + kx;
      vld[t] = v;
      fidx[t] = v ? (((pp >> 6) << 10) + (pp & 63)) : selfidx;
    }
  float acc[OPT];
#pragma unroll
  for (int o = 0; o < OPT; ++o) acc[o] = 0.f;
  const float4* W4 = (const float4*)RW;
#pragma unroll
  for (int t = 0; t < 9; ++t) {
    const float4* wb = W4 + (size_t)(t * OC + ocb) * 16;
    int fi = fidx[t];
    bool v = vld[t];
#pragma unroll 4
    for (int c4 = 0; c4 < 16; ++c4) {
      float4 xv = make_float4(0.f, 0.f, 0.f, 0.f);
      if (v) xv = F4[fi + (c4 << 6)];
#pragma unroll
      for (int o = 0; o < OPT; ++o) {
        float4 wv = wb[o * 16 + c4];
        acc[o] = fmaf(xv.x, wv.x, fmaf(xv.y, wv.y, fmaf(xv.z, wv.z, fmaf(xv.w, wv.w, acc[o]))));
      }
    }
  }
  if (px >= P_TOT) return;
  int ocdiv = OC >> 2;
  if constexpr ((OPT & 3) == 0) {
    float4* O4 = (float4*)O;
#pragma unroll
    for (int q = 0; q < OPT / 4; ++q) {
      float4 r;
      float v0 = acc[q*4+0] + bias[ocb+q*4+0];
      float v1 = acc[q*4+1] + bias[ocb+q*4+1];
      float v2 = acc[q*4+2] + bias[ocb+q*4+2];
      float v3 = acc[q*4+3] + bias[ocb+q*4+3];
      if (relu) { v0 = fmaxf(v0,0.f); v1 = fmaxf(v1,0.f); v2 = fmaxf(v2,0.f); v3 = fmaxf(v3,0.f); }
      r.x = v0; r.y = v1; r.z = v2; r.w = v3;
      O4[(size_t)blockIdx.x * (ocdiv << 6) + (((ocb >> 2) + q) << 6) + lane] = r;
    }
  } else {
#pragma unroll
    for (int o = 0; o < OPT; ++o) {
      float v = acc[o] + bias[ocb + o];
      if (relu) v = fmaxf(v, 0.f);
      int oc = ocb + o;
      O[((size_t)blockIdx.x * ocdiv + (oc >> 2)) * 256 + lane * 4 + (oc & 3)] = v;
    }
  }
}

// merged reg+cls 64->64 layer: waves 0-1 -> reg chain, waves 2-3(+gy) -> cls chain
__global__ __launch_bounds__(256) void k_conv3m(const float4* __restrict__ Fr, const float4* __restrict__ Fc,
                        float4* __restrict__ Or, float4* __restrict__ Oc,
                        const float* __restrict__ RWr, const float* __restrict__ RWc,
                        const float* __restrict__ br, const float* __restrict__ bc) {
  int S = blockIdx.x * 64;
  int l, off, W, sh; level_of(S, l, off, W, sh);
  int lane = threadIdx.x & 63;
  int wid = __builtin_amdgcn_readfirstlane(threadIdx.x >> 6);
  int g = blockIdx.y * 4 + wid;   // 0..15
  const float4* X; float4* O; const float* RW; const float* bias; int ocb;
  if (g < 8) { X = Fr; O = Or; RW = RWr; bias = br; ocb = g * 8; }
  else       { X = Fc; O = Oc; RW = RWc; bias = bc; ocb = (g - 8) * 8; }
  int px = S + lane;
  int loc = px - off, y = loc >> sh, x = loc & (W - 1);
  int selfidx = ((px >> 6) << 10) + (px & 63);
  int fidx[9]; bool vld[9];
#pragma unroll
  for (int ky = 0; ky < 3; ++ky)
#pragma unroll
    for (int kx = 0; kx < 3; ++kx) {
      int iy = y + ky - 1, ix = x + kx - 1;
      bool v = ((unsigned)iy < (unsigned)W) && ((unsigned)ix < (unsigned)W);
      int pp = px + (ky - 1) * W + (kx - 1);
      int t = ky * 3 + kx;
      vld[t] = v;
      fidx[t] = v ? (((pp >> 6) << 10) + (pp & 63)) : selfidx;
    }
  float acc[8];
#pragma unroll
  for (int o = 0; o < 8; ++o) acc[o] = 0.f;
  const float4* W4 = (const float4*)RW;
#pragma unroll
  for (int t = 0; t < 9; ++t) {
    const float4* wb = W4 + (size_t)(t * 64 + ocb) * 16;
    int fi = fidx[t];
    bool v = vld[t];
#pragma unroll 4
    for (int c4 = 0; c4 < 16; ++c4) {
      float4 xv = make_float4(0.f, 0.f, 0.f, 0.f);
      if (v) xv = X[fi + (c4 << 6)];
#pragma unroll
      for (int o = 0; o < 8; ++o) {
        float4 wv = wb[o * 16 + c4];
        acc[o] = fmaf(xv.x, wv.x, fmaf(xv.y, wv.y, fmaf(xv.z, wv.z, fmaf(xv.w, wv.w, acc[o]))));
      }
    }
  }
  if (px >= P_TOT) return;
#pragma unroll
  for (int q = 0; q < 2; ++q) {
    float4 r;
    r.x = fmaxf(acc[q*4+0] + bias[ocb+q*4+0], 0.f);
    r.y = fmaxf(acc[q*4+1] + bias[ocb+q*4+1], 0.f);
    r.z = fmaxf(acc[q*4+2] + bias[ocb+q*4+2], 0.f);
    r.w = fmaxf(acc[q*4+3] + bias[ocb+q*4+3], 0.f);
    O[(blockIdx.x << 10) + (((ocb >> 2) + q) << 6) + lane] = r;
  }
}

// ---------------- decode boxes + score/label (blocked reads) ----------------
__global__ void k_decode_score(const float4* __restrict__ REG4, const float4* __restrict__ CLS4,
                               float* __restrict__ score, int* __restrict__ label,
                               float* __restrict__ boxes, u32* __restrict__ ukey,
                               u32* __restrict__ hist1) {
  int aid = blockIdx.x * 256 + threadIdx.x;
  if (aid >= NANCH) return;
  int p = aid / 9;
  int a = aid - p * 9;
  int l, off, W, sh; level_of(p, l, off, W, sh);
  int loc = p - off, y = loc >> sh, x = loc & (W - 1);
  int s_idx = a % 3, r_idx = a / 3;
  double scale = (s_idx == 0) ? 1.0 : ((s_idx == 1) ? 1.2599210498948732 : 1.5874010519681994);
  double ratio = (r_idx == 0) ? 0.5 : ((r_idx == 1) ? 1.0 : 2.0);
  double strided = (double)(8 << l);
  double based = (double)(32 << l);
  double w0 = based * scale;
  double wA = sqrt(w0 * w0 / ratio);
  double hA = wA * ratio;
  double cxd = (x + 0.5) * strided;
  double cyd = (y + 0.5) * strided;
  float ax1 = (float)(cxd - wA / 2.0);
  float ay1 = (float)(cyd - hA / 2.0);
  float ax2 = (float)(cxd + wA / 2.0);
  float ay2 = (float)(cyd + hA / 2.0);
  float wa = ax2 - ax1, ha = ay2 - ay1;
  float cxa = ax1 + 0.5f * wa, cya = ay1 + 0.5f * ha;
  int blk = p >> 6, pxin = p & 63;
  float4 rq = REG4[blk * 576 + (a << 6) + pxin];
  float ncx = cxa + (rq.x * 0.1f) * wa;
  float ncy = cya + (rq.y * 0.1f) * ha;
  float nw = expf(rq.z * 0.2f) * wa;
  float nh = expf(rq.w * 0.2f) * ha;
  float bx1 = fmaxf(ncx - 0.5f * nw, 0.f);
  float by1 = fmaxf(ncy - 0.5f * nh, 0.f);
  float bx2 = fminf(ncx + 0.5f * nw, 512.f);
  float by2 = fminf(ncy + 0.5f * nh, 512.f);
  boxes[aid * 4 + 0] = bx1; boxes[aid * 4 + 1] = by1;
  boxes[aid * 4 + 2] = bx2; boxes[aid * 4 + 3] = by2;
  int cbase = blk * 11520 + ((a * 20) << 6) + pxin;
  float best = -1e30f; int bl = 0;
#pragma unroll 4
  for (int j = 0; j < 20; ++j) {
    float4 v4 = CLS4[cbase + (j << 6)];
    int c0 = j * 4;
    if (v4.x > best) { best = v4.x; bl = c0 + 0; }
    if (v4.y > best) { best = v4.y; bl = c0 + 1; }
    if (v4.z > best) { best = v4.z; bl = c0 + 2; }
    if (v4.w > best) { best = v4.w; bl = c0 + 3; }
  }
  float sc = 1.f / (1.f + expf(-best));
  score[aid] = sc; label[aid] = bl;
  u32 u = 0u;
  if (sc > 0.05f) u = __float_as_uint(sc) | 0x80000000u;
  ukey[aid] = u;
  if (u) atomicAdd(&hist1[u >> 16], 1u);
}

// ---------------- radix-select scans ----------------
__global__ __launch_bounds__(1024) void k_scanA(const u32* __restrict__ hist, u32* __restrict__ ctrl) {
  __shared__ u32 cs[1024];
  u32 s = 0;
  int base = threadIdx.x * 64;
  for (int b = 0; b < 64; ++b) s += hist[base + b];
  cs[threadIdx.x] = s;
  __syncthreads();
  if (threadIdx.x == 0) {
    u32 cum = 0; int cc = -1;
    for (int tt = 1023; tt >= 0; --tt) {
      if (cum + cs[tt] >= (u32)KTOP) { cc = tt; break; }
      cum += cs[tt];
    }
    if (cc < 0) {
      ctrl[0] = 0x20000u; ctrl[1] = cum; ctrl[2] = 1u;
    } else {
      u32 c2 = cum; int B1 = cc * 64;
      for (int b = cc * 64 + 63; b >= cc * 64; --b) {
        u32 h = hist[b];
        if (c2 + h >= (u32)KTOP) { B1 = b; break; }
        c2 += h;
      }
      ctrl[0] = (u32)B1; ctrl[1] = c2;
    }
  }
}

__global__ void k_histB(const u32* __restrict__ ukey, u32* __restrict__ hist2,
                        const u32* __restrict__ ctrl) {
  int aid = blockIdx.x * 256 + threadIdx.x;
  if (aid >= NANCH) return;
  u32 u = ukey[aid];
  if (u && (u >> 16) == ctrl[0]) atomicAdd(&hist2[u & 0xFFFFu], 1u);
}

__global__ __launch_bounds__(1024) void k_scanB(const u32* __restrict__ hist, u32* __restrict__ ctrl) {
  if (ctrl[0] > 0xFFFFu) return;
  __shared__ u32 cs[1024];
  u32 s = 0;
  int base = threadIdx.x * 64;
  for (int b = 0; b < 64; ++b) s += hist[base + b];
  cs[threadIdx.x] = s;
  __syncthreads();
  if (threadIdx.x == 0) {
    u32 CA = ctrl[1];
    u32 cum = CA; int cc = -1;
    for (int tt = 1023; tt >= 0; --tt) {
      if (cum + cs[tt] >= (u32)KTOP) { cc = tt; break; }
      cum += cs[tt];
    }
    u32 B2 = 0;
    if (cc >= 0) {
      for (int b = cc * 64 + 63; b >= cc * 64; --b) {
        u32 h = hist[b];
        if (cum + h >= (u32)KTOP) { B2 = (u32)b; break; }
        cum += h;
      }
    }
    ctrl[2] = (ctrl[0] << 16) | B2;
  }
}

__global__ void k_compact(const u32* __restrict__ ukey, u64* __restrict__ cand,
                          u32* __restrict__ ctrl) {
  int aid = blockIdx.x * 256 + threadIdx.x;
  if (aid >= NANCH) return;
  u32 u = ukey[aid];
  u32 T = ctrl[2];
  if (u >= T && u != 0) {
    u32 pos = atomicAdd(&ctrl[3], 1u);
    if (pos < (u32)CAND_CAP)
      cand[pos] = (((u64)u) << 32) | (u32)(~(u32)aid);
  }
}

// ---------------- bitonic sort + select top-1000 ----------------
__global__ __launch_bounds__(1024) void k_sortsel(const u64* __restrict__ cand, u32* __restrict__ ctrl,
                                                  const float* __restrict__ score, const int* __restrict__ label,
                                                  const float* __restrict__ boxes,
                                                  float* __restrict__ tops, int* __restrict__ topl,
                                                  float* __restrict__ topb) {
  __shared__ u64 key[CAND_CAP];
  int C = min((int)ctrl[3], CAND_CAP);
  for (int i = threadIdx.x; i < CAND_CAP; i += 1024) key[i] = (i < C) ? cand[i] : 0ULL;
  __syncthreads();
  for (int k = 2; k <= CAND_CAP; k <<= 1) {
    for (int j = k >> 1; j > 0; j >>= 1) {
      for (int t = threadIdx.x; t < CAND_CAP / 2; t += 1024) {
        int i1 = ((t & ~(j - 1)) << 1) | (t & (j - 1));
        int i2 = i1 + j;
        bool up = (i1 & k) != 0;
        u64 a = key[i1], b = key[i2];
        bool sw = up ? (a > b) : (a < b);
        if (sw) { key[i1] = b; key[i2] = a; }
      }
      __syncthreads();
    }
  }
  if (threadIdx.x < KTOP) {
    int r = threadIdx.x;
    u64 kk = key[r];
    u32 u = (u32)(kk >> 32);
    if (u != 0) {
      int aid = (int)(~((u32)kk));
      float sv = __uint_as_float(u & 0x7FFFFFFFu);
      tops[r] = sv; topl[r] = label[aid];
      topb[r * 4 + 0] = boxes[aid * 4 + 0];
      topb[r * 4 + 1] = boxes[aid * 4 + 1];
      topb[r * 4 + 2] = boxes[aid * 4 + 2];
      topb[r * 4 + 3] = boxes[aid * 4 + 3];
    } else {
      tops[r] = -1.f; topl[r] = -1;
      topb[r * 4 + 0] = 0.f; topb[r * 4 + 1] = 0.f;
      topb[r * 4 + 2] = 0.f; topb[r * 4 + 3] = 0.f;
    }
  }
  if (threadIdx.x == 0) ctrl[4] = (u32)min(C, KTOP);
}

// ---------------- NMS ----------------
__global__ void k_iou(const float* __restrict__ topb, const u32* __restrict__ ctrl,
                      u64* __restrict__ mask) {
  int wid = threadIdx.x >> 6, lane = threadIdx.x & 63;
  int i = blockIdx.x * 4 + wid;
  int V = (int)ctrl[4];
  if (i >= V) return;
  float x1i = topb[i * 4], y1i = topb[i * 4 + 1], x2i = topb[i * 4 + 2], y2i = topb[i * 4 + 3];
  float ai = fmaxf(x2i - x1i, 0.f) * fmaxf(y2i - y1i, 0.f);
  for (int w = 0; w < 16; ++w) {
    int j = w * 64 + lane;
    bool bit = false;
    if (j < KTOP && j > i) {
      float x1j = topb[j * 4], y1j = topb[j * 4 + 1], x2j = topb[j * 4 + 2], y2j = topb[j * 4 + 3];
      float aj = fmaxf(x2j - x1j, 0.f) * fmaxf(y2j - y1j, 0.f);
      float iw = fmaxf(fminf(x2i, x2j) - fmaxf(x1i, x1j), 0.f);
      float ih = fmaxf(fminf(y2i, y2j) - fmaxf(y1i, y1j), 0.f);
      float inter = iw * ih;
      float iou = inter / (ai + aj - inter + 1e-8f);
      bit = iou > 0.5f;
    }
    u64 m = __ballot(bit);
    if (lane == 0) mask[i * 16 + w] = m;
  }
}

__global__ __launch_bounds__(64) void k_nms(const u64* __restrict__ mask,
                                            const float* __restrict__ tops,
                                            int* __restrict__ keep) {
  const int la = threadIdx.x;
  const int rg = la >> 4;
  const int wg = la & 15;
  u64 remw = 0ULL;

#define LOADB(b, upd, intra, vsc) do {                                   \
    int rb = (b) * 64;                                                   \
    _Pragma("unroll")                                                    \
    for (int k = 0; k < 16; ++k)                                         \
      upd[k] = mask[(u32)(rb + rg + 4 * k) * 16u + (u32)wg];             \
    intra = mask[(u32)(rb + la) * 16u + (u32)(b)];                       \
    vsc = tops[rb + la];                                                 \
  } while (0)

#define PROC(b, upd, intra, vsc) do {                                    \
    u64 validmask = __ballot((vsc) > 0.05f);                             \
    u32 ilo = (u32)(intra);                                              \
    u32 ihi = (u32)((intra) >> 32);                                      \
    u64 supmask = ((u64)__builtin_amdgcn_readlane((int)(remw >> 32), (b)) << 32) | \
                  (u32)__builtin_amdgcn_readlane((int)(u32)remw, (b));   \
    u64 keptmask = 0ULL;                                                 \
    for (int i = 0; i < 64; ++i) {                                       \
      u32 rlo = (u32)__builtin_amdgcn_readlane((int)ilo, i);             \
      u32 rhi = (u32)__builtin_amdgcn_readlane((int)ihi, i);             \
      u64 take = (u64)0 - (((validmask >> i) & 1ULL) & (~(supmask >> i) & 1ULL)); \
      keptmask |= (1ULL << i) & take;                                    \
      supmask |= (((u64)rhi << 32) | rlo) & take;                        \
    }                                                                    \
    u64 kk = keptmask >> rg;                                             \
    u64 acc = 0ULL;                                                      \
    _Pragma("unroll")                                                    \
    for (int k = 0; k < 16; ++k)                                         \
      if ((kk >> (4 * k)) & 1ULL) acc |= upd[k];                         \
    acc |= __shfl_xor(acc, 16);                                          \
    acc |= __shfl_xor(acc, 32);                                          \
    remw |= acc;                                                         \
    int j = (b) * 64 + la;                                               \
    if (j < KTOP) keep[j] = (int)((keptmask >> la) & 1ULL);              \
  } while (0)

  u64 updA[16], updB[16];
  u64 intraA, intraB;
  float vscA, vscB;
  LOADB(0, updA, intraA, vscA);
  for (int bb = 0; bb < 16; bb += 2) {
    if (bb + 1 < 16) LOADB(bb + 1, updB, intraB, vscB);
    PROC(bb, updA, intraA, vscA);
    if (bb + 2 < 16) LOADB(bb + 2, updA, intraA, vscA);
    if (bb + 1 < 16) PROC(bb + 1, updB, intraB, vscB);
  }
#undef LOADB
#undef PROC
}

__global__ void k_final(const int* __restrict__ keep, const float* __restrict__ tops,
                        const int* __restrict__ topl, const float* __restrict__ topb,
                        float* __restrict__ out) {
  int r = blockIdx.x * 256 + threadIdx.x;
  if (r >= KTOP) return;
  int k = keep[r];
  out[r] = k ? tops[r] : 0.f;
  out[KTOP + r] = k ? (float)topl[r] : -1.f;
  out[2 * KTOP + r * 4 + 0] = k ? topb[r * 4 + 0] : 0.f;
  out[2 * KTOP + r * 4 + 1] = k ? topb[r * 4 + 1] : 0.f;
  out[2 * KTOP + r * 4 + 2] = k ? topb[r * 4 + 2] : 0.f;
  out[2 * KTOP + r * 4 + 3] = k ? topb[r * 4 + 3] : 0.f;
}

extern "C" void kernel_launch(void* const* d_in, const int* in_sizes, int n_in,
                              void* d_out, int out_size, void* d_ws, size_t ws_size,
                              hipStream_t stream) {
  const float* c3    = (const float*)d_in[0];
  const float* c4i   = (const float*)d_in[1];
  const float* c5    = (const float*)d_in[2];
  const float* w3    = (const float*)d_in[3];  const float* b3 = (const float*)d_in[4];
  const float* w4    = (const float*)d_in[5];  const float* b4 = (const float*)d_in[6];
  const float* w5    = (const float*)d_in[7];  const float* b5 = (const float*)d_in[8];
  const float* w6    = (const float*)d_in[9];  const float* b6 = (const float*)d_in[10];
  const float* w7    = (const float*)d_in[11]; const float* b7 = (const float*)d_in[12];
  const float* tdw   = (const float*)d_in[13]; const float* tdb  = (const float*)d_in[14];
  const float* tdg   = (const float*)d_in[15]; const float* tdbt = (const float*)d_in[16];
  const float* tdm   = (const float*)d_in[17]; const float* tdv  = (const float*)d_in[18];
  const float* ow    = (const float*)d_in[19]; const float* ob   = (const float*)d_in[20];
  const float* og    = (const float*)d_in[21]; const float* obt  = (const float*)d_in[22];
  const float* om    = (const float*)d_in[23]; const float* ov   = (const float*)d_in[24];
  const float* w1    = (const float*)d_in[25]; const float* w2   = (const float*)d_in[26];
  const float* clsw  = (const float*)d_in[27]; const float* clsb = (const float*)d_in[28];
  const float* clsow = (const float*)d_in[29]; const float* clsob= (const float*)d_in[30];
  const float* regw  = (const float*)d_in[31]; const float* regb = (const float*)d_in[32];
  const float* regow = (const float*)d_in[33]; const float* regob= (const float*)d_in[34];

  float* ws = (float*)d_ws;
  const size_t NF = 352256;                 // 86 blks * 4096 floats
  float* A    = ws;
  float* Bb   = ws + NF;
  float* Cb   = ws + 2 * NF;
  float* RWc  = ws + 3 * NF;                // 110592
  float* RWco = RWc + 110592;               // 414720
  float* RWr  = RWco + 414720;              // 110592
  float* RWro = RWr + 110592;               // 20736
  float* REGb = RWro + 20736;               // 198144 (86*2304)
  float* CLSb = REGb + 198144;              // 3962880 (86*46080)
  float* scoreb = CLSb + 3962880;           // 49104
  int*   labelb = (int*)(scoreb + 49104);   // 49104
  float* boxesb = (float*)(labelb + 49104); // 196416
  u32* hist1 = (u32*)(boxesb + 196416);     // 65536
  u32* hist2 = hist1 + 65536;               // 65536
  u32* ctrl  = hist2 + 65536;               // 64
  u64* cand  = (u64*)(ctrl + 64);           // 4096 u64
  float* tops = (float*)(cand + CAND_CAP);  // 1024
  int*   topl = (int*)(tops + 1024);        // 1024
  float* topb = (float*)(topl + 1024);      // 4096
  u64*   mask = (u64*)(topb + 4096);        // 16384 u64
  int*   keep = (int*)(mask + 16384);       // 1024
  u32*   ukeyb = (u32*)(keep + 1024);       // 49104

  float4* A4 = (float4*)A; float4* B4 = (float4*)Bb; float4* C4 = (float4*)Cb;
  float4* REG4 = (float4*)REGb; float4* CLS4 = (float4*)CLSb;

  hipMemsetAsync(hist1, 0, (65536 + 65536 + 64) * sizeof(u32), stream);

  // weight repack (merged)
  k_repack_all<<<dim3(2565), 256, 0, stream>>>(clsw, regw, clsow, regow, RWc, RWr, RWco, RWro);

  // FPN inputs (batch 0 only) -> blocked layout
  k_conv1x1_in<<<dim3(16, 16), 256, 0, stream>>>(c3, w3, b3, A4, 40, 4096, 0);
  k_conv1x1_in<<<dim3(4, 16), 256, 0, stream>>>(c4i, w4, b4, A4, 80, 1024, 4096);
  k_conv1x1_c5<<<dim3(64), 256, 0, stream>>>(c5, w5, b5, A);
  k_conv_p6<<<dim3(64), 256, 0, stream>>>(c5, w6, b6, A);
  k_conv_p7<<<dim3(64), 64, 0, stream>>>(w7, b7, A);

  // BiFPN x2
  k_td_t<<<dim3(86), 256, 0, stream>>>(A4, B4, tdw, tdb, tdg, tdbt, tdm, tdv, w1, 0);
  k_out_t<<<dim3(86), 256, 0, stream>>>(A4, B4, C4, ow, ob, og, obt, om, ov, w2, 0);
  k_td_t<<<dim3(86), 256, 0, stream>>>(C4, B4, tdw, tdb, tdg, tdbt, tdm, tdv, w1, 1);
  k_out_t<<<dim3(86), 256, 0, stream>>>(C4, B4, A4, ow, ob, og, obt, om, ov, w2, 1);

  // heads: merged reg+cls 64->64 layers (A -> B/C -> ...), then output convs
  // layer1: reg: A->Bb ; cls: A->Cb
  k_conv3m<<<dim3(86, 4), 256, 0, stream>>>(A4, A4, B4, C4, RWr, RWc, regb, clsb);
  // layer2: reg: Bb->A ; cls: Cb->? (need distinct buffers: reg Bb->?; reuse)
  // reg chain: A -> Bb -> (layer2) -> Cb? Cb holds cls. Allocate via swap:
  // l2: reg Bb -> A? A still needed as cls l2 input? No: cls l2 input is Cb.
  k_conv3m<<<dim3(86, 4), 256, 0, stream>>>(B4, C4, A4, B4, RWr + 36864, RWc + 36864, regb + 64, clsb + 64);
  // now reg l3 input = A, cls l3 input = Bb
  k_conv3m<<<dim3(86, 4), 256, 0, stream>>>(A4, B4, C4, A4, RWr + 73728, RWc + 73728, regb + 128, clsb + 128);
  // reg final features in Cb, cls final features in A
  k_conv3t<9><<<dim3(86, 1), 256, 0, stream>>>(C4, REGb, RWro, regob, 36, 0);
  k_conv3t<8><<<dim3(86, 23), 256, 0, stream>>>(A4, CLSb, RWco, clsob, 720, 0);

  // decode + score + top-k + NMS
  k_decode_score<<<dim3(192), 256, 0, stream>>>(REG4, CLS4, scoreb, labelb, boxesb, ukeyb, hist1);
  k_scanA<<<dim3(1), 1024, 0, stream>>>(hist1, ctrl);
  k_histB<<<dim3(192), 256, 0, stream>>>(ukeyb, hist2, ctrl);
  k_scanB<<<dim3(1), 1024, 0, stream>>>(hist2, ctrl);
  k_compact<<<dim3(192), 256, 0, stream>>>(ukeyb, cand, ctrl);
  k_sortsel<<<dim3(1), 1024, 0, stream>>>(cand, ctrl, scoreb, labelb, boxesb, tops, topl, topb);
  k_iou<<<dim3(250), 256, 0, stream>>>(topb, ctrl, mask);
  k_nms<<<dim3(1), 64, 0, stream>>>(mask, tops, keep);
  k_final<<<dim3(4), 256, 0, stream>>>(keep, tops, topl, topb, (float*)d_out);
}